// Round 1
// baseline (433.689 us; speedup 1.0000x reference)
//
#include <hip/hip_runtime.h>

typedef float v2f __attribute__((ext_vector_type(2)));

#define HID 10
#define NIN 6
#define SEQT 512
#define TC 16
#define NCHUNK (SEQT/TC)
#define BPB 64            // batches per block (4 lanes per batch * 64 = 256 threads)
#define NTHR 256
#define XSTRIDE 100       // floats per batch row in LDS (16*6=96 + 4 pad; 8B aligned, 2-way max bank alias)

// broadcast lane L (0..3) of each quad via DPP quad_perm (full-rate VALU)
#define QB(v, L) __int_as_float(__builtin_amdgcn_mov_dpp(__float_as_int(v), (L)*0x55, 0xf, 0xf, true))

__device__ __forceinline__ float fast_exp2(float x){ float r; asm("v_exp_f32 %0, %1" : "=v"(r) : "v"(x)); return r; }
__device__ __forceinline__ float fast_rcp (float x){ float r; asm("v_rcp_f32 %0, %1" : "=v"(r) : "v"(x)); return r; }

__global__ __launch_bounds__(NTHR, 1)
void Model_88459146428723_kernel(const float* __restrict__ x,
                                 const float* __restrict__ Wih,
                                 const float* __restrict__ Whh,
                                 const float* __restrict__ bih,
                                 const float* __restrict__ bhh,
                                 const float* __restrict__ Wfc,
                                 const float* __restrict__ bfc,
                                 float* __restrict__ out)
{
    __shared__ float xs[2][BPB*XSTRIDE];   // 51.2 KB double-buffered x tile
    const int tid = threadIdx.x;
    const int typ = tid & 3;               // gate type: 0=i,1=f,2=g(tanh),3=o
    const int bl  = tid >> 2;              // local batch index 0..63

    // ---- preload my gate-type's weight rows into registers ----
    v2f   wih[HID][3];
    v2f   whh[HID][5];
    float bias[HID];
    {
        const int g0 = typ*HID;
        #pragma unroll
        for (int u=0; u<HID; ++u){
            const float* wi = Wih + (size_t)(g0+u)*NIN;
            #pragma unroll
            for (int k=0; k<3; ++k){ v2f t = {wi[2*k], wi[2*k+1]}; wih[u][k] = t; }
            const float* wh = Whh + (size_t)(g0+u)*HID;
            #pragma unroll
            for (int k=0; k<5; ++k){ v2f t = {wh[2*k], wh[2*k+1]}; whh[u][k] = t; }
            bias[u] = bih[g0+u] + bhh[g0+u];
        }
    }
    // branch-free activation constants: sigmoid for i,f,o; tanh = 2*sigmoid(2x)-1 for g
    const float expk = (typ==2) ? -2.8853900817779268f : -1.4426950408889634f; // -(1|2)*log2(e)
    const float pm   = (typ==2) ?  2.0f : 1.0f;
    const float pa   = (typ==2) ? -1.0f : 0.0f;

    const float* xrow = x + (size_t)blockIdx.x * BPB * (SEQT*NIN);
    float4 stage[6];

    auto load_chunk = [&](int cidx){
        #pragma unroll
        for (int k=0; k<6; ++k){
            int f = tid + k*NTHR;          // float4 index in [0,1536)
            int r = f/24, col = f - r*24;  // 24 float4 per batch-row per chunk
            stage[k] = *reinterpret_cast<const float4*>(
                xrow + (size_t)r*(SEQT*NIN) + cidx*(TC*NIN) + col*4);
        }
    };
    auto write_chunk = [&](int buf){
        #pragma unroll
        for (int k=0; k<6; ++k){
            int f = tid + k*NTHR;
            int r = f/24, col = f - r*24;
            *reinterpret_cast<float4*>(&xs[buf][r*XSTRIDE + col*4]) = stage[k];
        }
    };

    load_chunk(0); write_chunk(0); __syncthreads();

    v2f   hp[5];                 // hidden state as float2 pairs (replicated across quad)
    float cst[HID];              // cell state (replicated across quad)
    #pragma unroll
    for (int k=0; k<5; ++k){ v2f z = {0.f,0.f}; hp[k] = z; }
    #pragma unroll
    for (int u=0; u<HID; ++u) cst[u] = 0.f;

    for (int ch=0; ch<NCHUNK; ++ch){
        const float* xb = &xs[ch&1][bl*XSTRIDE];
        if (ch+1 < NCHUNK) load_chunk(ch+1);     // global -> regs, consumed ~16 steps later

        v2f xp[3];
        #pragma unroll
        for (int k=0; k<3; ++k) xp[k] = *reinterpret_cast<const v2f*>(xb + 2*k);

        #pragma unroll 2
        for (int tt=0; tt<TC; ++tt){
            // prefetch next step's x (wraps harmlessly at chunk end)
            v2f xn[3];
            const int tn = (tt+1) & (TC-1);
            #pragma unroll
            for (int k=0; k<3; ++k) xn[k] = *reinterpret_cast<const v2f*>(xb + tn*NIN + 2*k);

            // 10 gate pre-activations for my gate type
            float s[HID];
            #pragma unroll
            for (int u=0; u<HID; ++u){
                v2f acc = {bias[u], 0.f};
                #pragma unroll
                for (int k=0; k<3; ++k) acc = __builtin_elementwise_fma(xp[k], wih[u][k], acc);
                #pragma unroll
                for (int k=0; k<5; ++k) acc = __builtin_elementwise_fma(hp[k], whh[u][k], acc);
                s[u] = acc.x + acc.y;
            }
            // branch-free activation
            float act[HID];
            #pragma unroll
            for (int u=0; u<HID; ++u){
                float e = fast_exp2(s[u]*expk);
                act[u] = fmaf(pm, fast_rcp(1.0f + e), pa);
            }
            // share across quad (DPP broadcasts) + replicated c/h update
            #pragma unroll
            for (int u=0; u<HID; ++u){
                float ia = QB(act[u], 0);
                float fa = QB(act[u], 1);
                float ga = QB(act[u], 2);
                float oa = QB(act[u], 3);
                float cu = fmaf(fa, cst[u], ia*ga);
                cst[u] = cu;
                float e  = fast_exp2(cu * -2.8853900817779268f);
                float th = fmaf(2.0f, fast_rcp(1.0f + e), -1.0f);   // tanh(cu)
                float hu = oa * th;
                if (u & 1) hp[u>>1].y = hu; else hp[u>>1].x = hu;
            }
            #pragma unroll
            for (int k=0; k<3; ++k) xp[k] = xn[k];
        }
        if (ch+1 < NCHUNK) write_chunk((ch+1)&1);
        __syncthreads();
    }

    // final FC + sigmoid: lanes 0,1 of each quad produce the 2 outputs
    if (typ < 2){
        float a = bfc[typ];
        const float* wf = Wfc + typ*HID;
        #pragma unroll
        for (int k=0; k<5; ++k){
            a = fmaf(hp[k].x, wf[2*k],   a);
            a = fmaf(hp[k].y, wf[2*k+1], a);
        }
        float e = fast_exp2(a * -1.4426950408889634f);
        const int b = blockIdx.x*BPB + bl;
        out[(size_t)b*2 + typ] = fast_rcp(1.0f + e);
    }
}

extern "C" void kernel_launch(void* const* d_in, const int* in_sizes, int n_in,
                              void* d_out, int out_size, void* d_ws, size_t ws_size,
                              hipStream_t stream) {
    const float* x   = (const float*)d_in[0];
    const float* Wih = (const float*)d_in[1];
    const float* Whh = (const float*)d_in[2];
    const float* bih = (const float*)d_in[3];
    const float* bhh = (const float*)d_in[4];
    const float* Wfc = (const float*)d_in[5];
    const float* bfc = (const float*)d_in[6];
    float* out = (float*)d_out;

    dim3 grid(16384 / BPB);   // 256 blocks -> 1 per CU
    dim3 block(NTHR);
    Model_88459146428723_kernel<<<grid, block, 0, stream>>>(x, Wih, Whh, bih, bhh, Wfc, bfc, out);
}

// Round 2
// 302.942 us; speedup vs baseline: 1.4316x; 1.4316x over previous
//
#include <hip/hip_runtime.h>

typedef float v2f __attribute__((ext_vector_type(2)));

#define HID 10
#define NIN 6
#define SEQT 512
#define TC 16
#define NCHUNK (SEQT/TC)
#define BPB 32            // batches per block (8 lanes per batch * 32 = 256 threads)
#define NTHR 256
#define XSTRIDE 100       // floats per batch row in LDS (16*6=96 + 4 pad)

// broadcast lane L (0..3) of each quad via DPP quad_perm (full-rate VALU)
#define QB(v, L) __int_as_float(__builtin_amdgcn_mov_dpp(__float_as_int(v), (L)*0x55, 0xf, 0xf, true))
// exchange lane l <-> 7-l within each 8-lane group (row_half_mirror)
#define HMIR(v)  __int_as_float(__builtin_amdgcn_mov_dpp(__float_as_int(v), 0x141, 0xf, 0xf, true))

__device__ __forceinline__ float fast_exp2(float x){ float r; asm("v_exp_f32 %0, %1" : "=v"(r) : "v"(x)); return r; }
__device__ __forceinline__ float fast_rcp (float x){ float r; asm("v_rcp_f32 %0, %1" : "=v"(r) : "v"(x)); return r; }

// Lane decomposition: 8 lanes per batch.
//   typ  = lane&3 : gate type 0=i,1=f,2=g(tanh),3=o
//   half = (lane>>2)&1 : u-parity — half 0 owns even u {0,2,4,6,8}, half 1 odd u
// Each lane computes 5 gate pre-activations (its typ, its parity's 5 u's).
// Gates are shared within a quad via quad_perm; each quad updates its parity's
// 5 c/h entries; halves exchange h via row_half_mirror. h is stored as v2f
// pairs (h[2k+half], h[2k+1-half]) — weight pair components are loaded
// per-lane-swapped so the packed FMA is layout-uniform (no cndmasks).
__global__ __launch_bounds__(NTHR, 2)
void Model_88459146428723_kernel(const float* __restrict__ x,
                                 const float* __restrict__ Wih,
                                 const float* __restrict__ Whh,
                                 const float* __restrict__ bih,
                                 const float* __restrict__ bhh,
                                 const float* __restrict__ Wfc,
                                 const float* __restrict__ bfc,
                                 float* __restrict__ out)
{
    __shared__ float xs[2][BPB*XSTRIDE];   // 25.6 KB double-buffered x tile
    const int tid = threadIdx.x;
    const int l8  = tid & 7;
    const int typ = tid & 3;
    const int hf  = (tid >> 2) & 1;
    const int bl  = tid >> 3;              // local batch 0..31

    // ---- preload weights: 5 rows (typ, u = 2*uu+hf) ----
    v2f   wih[5][3];
    v2f   whh[5][5];
    float bias[5];
    #pragma unroll
    for (int uu=0; uu<5; ++uu){
        const int row = typ*HID + 2*uu + hf;
        const float* wi = Wih + (size_t)row*NIN;
        #pragma unroll
        for (int k=0; k<3; ++k){ v2f t = {wi[2*k], wi[2*k+1]}; wih[uu][k] = t; }
        const float* wh = Whh + (size_t)row*HID;
        #pragma unroll
        for (int k=0; k<5; ++k){ v2f t = {wh[2*k + hf], wh[2*k + 1 - hf]}; whh[uu][k] = t; }
        bias[uu] = bih[row] + bhh[row];
    }
    // branch-free activation constants: sigmoid for i,f,o; tanh = 2*sigmoid(2x)-1 for g
    const float expk = (typ==2) ? -2.8853900817779268f : -1.4426950408889634f;
    const float pm   = (typ==2) ?  2.0f : 1.0f;
    const float pa   = (typ==2) ? -1.0f : 0.0f;

    const float* xrow = x + (size_t)blockIdx.x * BPB * (SEQT*NIN);
    float4 stage[3];

    auto load_chunk = [&](int cidx){
        #pragma unroll
        for (int k=0; k<3; ++k){
            int f = tid + k*NTHR;          // float4 index in [0,768)
            int r = f/24, col = f - r*24;  // 24 float4 per batch-row per chunk
            stage[k] = *reinterpret_cast<const float4*>(
                xrow + (size_t)r*(SEQT*NIN) + cidx*(TC*NIN) + col*4);
        }
    };
    auto write_chunk = [&](int buf){
        #pragma unroll
        for (int k=0; k<3; ++k){
            int f = tid + k*NTHR;
            int r = f/24, col = f - r*24;
            *reinterpret_cast<float4*>(&xs[buf][r*XSTRIDE + col*4]) = stage[k];
        }
    };

    load_chunk(0); write_chunk(0); __syncthreads();

    v2f   hp[5];     // h pairs: hp[k] = (h[2k+hf], h[2k+1-hf]) — replicated in 8-group
    float cst[5];    // c for my parity's u's (replicated within quad)
    #pragma unroll
    for (int k=0; k<5; ++k){ v2f z = {0.f,0.f}; hp[k] = z; cst[k] = 0.f; }

    for (int ch=0; ch<NCHUNK; ++ch){
        const float* xb = &xs[ch&1][bl*XSTRIDE];
        if (ch+1 < NCHUNK) load_chunk(ch+1);     // global -> regs, consumed 16 steps later

        v2f xp[3];
        #pragma unroll
        for (int k=0; k<3; ++k) xp[k] = *reinterpret_cast<const v2f*>(xb + 2*k);

        #pragma unroll 2
        for (int tt=0; tt<TC; ++tt){
            // prefetch next step's x (wraps harmlessly at chunk end)
            v2f xn[3];
            const int tn = (tt+1) & (TC-1);
            #pragma unroll
            for (int k=0; k<3; ++k) xn[k] = *reinterpret_cast<const v2f*>(xb + tn*NIN + 2*k);

            // 5 gate pre-activations (my typ, my parity)
            float s[5];
            #pragma unroll
            for (int uu=0; uu<5; ++uu){
                v2f acc = {bias[uu], 0.f};
                #pragma unroll
                for (int k=0; k<3; ++k) acc = __builtin_elementwise_fma(xp[k], wih[uu][k], acc);
                #pragma unroll
                for (int k=0; k<5; ++k) acc = __builtin_elementwise_fma(hp[k], whh[uu][k], acc);
                s[uu] = acc.x + acc.y;
            }
            // branch-free activation
            float act[5];
            #pragma unroll
            for (int uu=0; uu<5; ++uu){
                float e = fast_exp2(s[uu]*expk);
                act[uu] = fmaf(pm, fast_rcp(1.0f + e), pa);
            }
            // quad gather, c/h update (my parity), cross-half h exchange
            #pragma unroll
            for (int uu=0; uu<5; ++uu){
                float ia = QB(act[uu], 0);
                float fa = QB(act[uu], 1);
                float ga = QB(act[uu], 2);
                float oa = QB(act[uu], 3);
                float cu = fmaf(fa, cst[uu], ia*ga);
                cst[uu] = cu;
                float e  = fast_exp2(cu * -2.8853900817779268f);
                float th = fmaf(2.0f, fast_rcp(1.0f + e), -1.0f);   // tanh(cu)
                float hmy = oa * th;                                // h[2uu+hf]
                float hot = HMIR(hmy);                              // h[2uu+1-hf]
                v2f hv = {hmy, hot};
                hp[uu] = hv;
            }
            #pragma unroll
            for (int k=0; k<3; ++k) xp[k] = xn[k];
        }
        if (ch+1 < NCHUNK) write_chunk((ch+1)&1);
        __syncthreads();
    }

    // final FC + sigmoid: lanes l8==0,1 (half 0 -> natural pair order) write the 2 outputs
    if (l8 < 2){
        float a = bfc[l8];
        const float* wf = Wfc + l8*HID;
        #pragma unroll
        for (int k=0; k<5; ++k){
            a = fmaf(hp[k].x, wf[2*k],   a);
            a = fmaf(hp[k].y, wf[2*k+1], a);
        }
        float e = fast_exp2(a * -1.4426950408889634f);
        const int b = blockIdx.x*BPB + bl;
        out[(size_t)b*2 + l8] = fast_rcp(1.0f + e);
    }
}

extern "C" void kernel_launch(void* const* d_in, const int* in_sizes, int n_in,
                              void* d_out, int out_size, void* d_ws, size_t ws_size,
                              hipStream_t stream) {
    const float* x   = (const float*)d_in[0];
    const float* Wih = (const float*)d_in[1];
    const float* Whh = (const float*)d_in[2];
    const float* bih = (const float*)d_in[3];
    const float* bhh = (const float*)d_in[4];
    const float* Wfc = (const float*)d_in[5];
    const float* bfc = (const float*)d_in[6];
    float* out = (float*)d_out;

    dim3 grid(16384 / BPB);   // 512 blocks -> 2 per CU -> 2 waves/SIMD
    dim3 block(NTHR);
    Model_88459146428723_kernel<<<grid, block, 0, stream>>>(x, Wih, Whh, bih, bhh, Wfc, bfc, out);
}